// Round 1
// baseline (4385.360 us; speedup 1.0000x reference)
//
#include <hip/hip_runtime.h>
#include <math.h>

#define LL 64
#define BB 8
#define HH 512
#define H2 1024
#define VV 8192
#define NSENT 63
#define NEGV (-1e9f)
#define EPSV 4.5399929762484854e-05f

// ---------------------------------------------------------------- init table
__global__ __launch_bounds__(256) void init_table_kernel(float* __restrict__ table) {
    int idx = blockIdx.x * 256 + threadIdx.x;
    table[idx] = NEGV;   // grid sized exactly
}

// ---------------------------------------------------------------- trans probs
// One block per (i,j), i<j. Computes p = sigmoid(BinaryClassifier(concat(enc_i,enc_j)))
// sh_log[i,j,b] = log1p(-p+EPS); red_log[i,j,b] = log(p+EPS)
__global__ __launch_bounds__(256) void trans_kernel(
    const float* __restrict__ enc, const float* __restrict__ W1t,
    const float* __restrict__ b1t, const float* __restrict__ W2t,
    const float* __restrict__ b2t, float* __restrict__ sh_log,
    float* __restrict__ red_log)
{
    const int i = blockIdx.x >> 6;
    const int j = blockIdx.x & 63;
    if (i >= j) return;

    __shared__ float f[BB][H2];       // 32 KB
    __shared__ float redm[4][BB];

    const float* ei = enc + (size_t)i * BB * HH;
    const float* ej = enc + (size_t)j * BB * HH;
    for (int t = threadIdx.x; t < BB * HH; t += 256) {
        int b = t >> 9;          // /512
        int k = t & 511;
        f[b][k] = ei[t];
        f[b][k + HH] = ej[t];
    }
    __syncthreads();

    const int u0 = threadIdx.x;      // this thread owns hidden units u0, u0+256
    float acc0[BB], acc1[BB];
#pragma unroll
    for (int b = 0; b < BB; b++) { acc0[b] = 0.f; acc1[b] = 0.f; }

    for (int k = 0; k < H2; k += 4) {
        float4 fk[BB];
#pragma unroll
        for (int b = 0; b < BB; b++) fk[b] = *(const float4*)&f[b][k];
#pragma unroll
        for (int kk = 0; kk < 4; kk++) {
            float w0 = W1t[(size_t)(k + kk) * HH + u0];
            float w1 = W1t[(size_t)(k + kk) * HH + u0 + 256];
#pragma unroll
            for (int b = 0; b < BB; b++) {
                float fb = ((const float*)&fk[b])[kk];
                acc0[b] = fmaf(fb, w0, acc0[b]);
                acc1[b] = fmaf(fb, w1, acc1[b]);
            }
        }
    }

    const float bias0 = b1t[u0], bias1 = b1t[u0 + 256];
    const float w2a = W2t[u0], w2b = W2t[u0 + 256];
    float part[BB];
#pragma unroll
    for (int b = 0; b < BB; b++) {
        float ha = acc0[b] + bias0; ha = ha > 0.f ? ha : 0.f;
        float hb = acc1[b] + bias1; hb = hb > 0.f ? hb : 0.f;
        part[b] = ha * w2a + hb * w2b;
    }
#pragma unroll
    for (int off = 32; off > 0; off >>= 1) {
#pragma unroll
        for (int b = 0; b < BB; b++)
            part[b] += __shfl_down(part[b], off, 64);
    }
    const int wave = threadIdx.x >> 6;
    const int lane = threadIdx.x & 63;
    if (lane == 0) {
#pragma unroll
        for (int b = 0; b < BB; b++) redm[wave][b] = part[b];
    }
    __syncthreads();
    if (threadIdx.x < BB) {
        const int b = threadIdx.x;
        float sc = redm[0][b] + redm[1][b] + redm[2][b] + redm[3][b] + b2t[0];
        float p = 1.f / (1.f + expf(-sc));
        sh_log[((size_t)i * LL + j) * BB + b]  = log1pf(-p + EPSV);
        red_log[((size_t)i * LL + j) * BB + b] = logf(p + EPSV);
    }
}

// ---------------------------------------------------------------- word model (fused)
// One block per needed pair: base pairs (i<j<=62) write table[i][j][j+1] = sh_log + g,
// the (0,0) block writes table[0][0][1] = g00.
// g = logit[sentence[j+1]] - logsumexp_v(logits); hidden kept in LDS, W2w streamed.
__global__ __launch_bounds__(256) void word_kernel(
    const float* __restrict__ enc, const int* __restrict__ sentence,
    const float* __restrict__ W1w, const float* __restrict__ b1w,
    const float* __restrict__ W2w, const float* __restrict__ b2w,
    const float* __restrict__ sh_log, float* __restrict__ table)
{
    const int i = blockIdx.x >> 6;
    const int j = blockIdx.x & 63;
    const bool root = (i == 0 && j == 0);
    if (!root && !(i < j && j <= NSENT - 1)) return;

    __shared__ float f[BB][H2];     // 32 KB
    __shared__ float h[BB][HH];     // 16 KB
    __shared__ float redm[4][BB];
    __shared__ float reds[4][BB];
    __shared__ float gval[BB];

    const float* ei = enc + (size_t)i * BB * HH;
    const float* ej = enc + (size_t)(root ? 0 : j) * BB * HH;
    for (int t = threadIdx.x; t < BB * HH; t += 256) {
        int b = t >> 9;
        int k = t & 511;
        f[b][k] = ei[t];
        f[b][k + HH] = ej[t];
    }
    __syncthreads();

    const int u0 = threadIdx.x;
    {   // hidden layer -> LDS h
        float acc0[BB], acc1[BB];
#pragma unroll
        for (int b = 0; b < BB; b++) { acc0[b] = 0.f; acc1[b] = 0.f; }
        for (int k = 0; k < H2; k += 4) {
            float4 fk[BB];
#pragma unroll
            for (int b = 0; b < BB; b++) fk[b] = *(const float4*)&f[b][k];
#pragma unroll
            for (int kk = 0; kk < 4; kk++) {
                float w0 = W1w[(size_t)(k + kk) * HH + u0];
                float w1 = W1w[(size_t)(k + kk) * HH + u0 + 256];
#pragma unroll
                for (int b = 0; b < BB; b++) {
                    float fb = ((const float*)&fk[b])[kk];
                    acc0[b] = fmaf(fb, w0, acc0[b]);
                    acc1[b] = fmaf(fb, w1, acc1[b]);
                }
            }
        }
        const float bias0 = b1w[u0], bias1 = b1w[u0 + 256];
#pragma unroll
        for (int b = 0; b < BB; b++) {
            float ha = acc0[b] + bias0;
            float hb = acc1[b] + bias1;
            h[b][u0] = ha > 0.f ? ha : 0.f;
            h[b][u0 + 256] = hb > 0.f ? hb : 0.f;
        }
    }
    __syncthreads();

    int wordId[BB];
    {
        const int row = root ? 1 : (j + 1);
#pragma unroll
        for (int b = 0; b < BB; b++) wordId[b] = sentence[row * BB + b];
    }

    float m[BB], s[BB];
#pragma unroll
    for (int b = 0; b < BB; b++) { m[b] = -3.4e38f; s[b] = 0.f; }

    // stream V in tiles of 1024 columns (4 per thread, float4 loads)
    for (int tile = 0; tile < VV; tile += 1024) {
        const int v = tile + (threadIdx.x << 2);
        float4 acc[BB];
#pragma unroll
        for (int b = 0; b < BB; b++) acc[b] = make_float4(0.f, 0.f, 0.f, 0.f);
        for (int k = 0; k < HH; k += 4) {
            float4 hk[BB];
#pragma unroll
            for (int b = 0; b < BB; b++) hk[b] = *(const float4*)&h[b][k];
#pragma unroll
            for (int kk = 0; kk < 4; kk++) {
                float4 w = *(const float4*)&W2w[(size_t)(k + kk) * VV + v];
#pragma unroll
                for (int b = 0; b < BB; b++) {
                    float hb = ((const float*)&hk[b])[kk];
                    acc[b].x = fmaf(hb, w.x, acc[b].x);
                    acc[b].y = fmaf(hb, w.y, acc[b].y);
                    acc[b].z = fmaf(hb, w.z, acc[b].z);
                    acc[b].w = fmaf(hb, w.w, acc[b].w);
                }
            }
        }
        const float4 bw = *(const float4*)&b2w[v];
#pragma unroll
        for (int b = 0; b < BB; b++) {
            float lg[4] = { acc[b].x + bw.x, acc[b].y + bw.y,
                            acc[b].z + bw.z, acc[b].w + bw.w };
#pragma unroll
            for (int c = 0; c < 4; c++) {
                float x = lg[c];
                if (x > m[b]) { s[b] = s[b] * __expf(m[b] - x) + 1.f; m[b] = x; }
                else          { s[b] += __expf(x - m[b]); }
                if (v + c == wordId[b]) gval[b] = x;   // unique writer per b
            }
        }
    }

    // combine (m,s) across the block
#pragma unroll
    for (int off = 32; off > 0; off >>= 1) {
#pragma unroll
        for (int b = 0; b < BB; b++) {
            float mo = __shfl_down(m[b], off, 64);
            float so = __shfl_down(s[b], off, 64);
            float M = fmaxf(m[b], mo);
            s[b] = s[b] * __expf(m[b] - M) + so * __expf(mo - M);
            m[b] = M;
        }
    }
    const int wave = threadIdx.x >> 6;
    const int lane = threadIdx.x & 63;
    if (lane == 0) {
#pragma unroll
        for (int b = 0; b < BB; b++) { redm[wave][b] = m[b]; reds[wave][b] = s[b]; }
    }
    __syncthreads();
    if (threadIdx.x < BB) {
        const int b = threadIdx.x;
        float M = redm[0][b];
#pragma unroll
        for (int w = 1; w < 4; w++) M = fmaxf(M, redm[w][b]);
        float S = 0.f;
#pragma unroll
        for (int w = 0; w < 4; w++) S += reds[w][b] * __expf(redm[w][b] - M);
        const float lse = M + logf(S);
        const float g = gval[b] - lse;
        if (root) {
            table[((size_t)(0 * LL + 0) * LL + 1) * BB + b] = g;
        } else {
            table[(((size_t)i * LL + j) * LL + (j + 1)) * BB + b] =
                sh_log[((size_t)i * LL + j) * BB + b] + g;
        }
    }
}

// ---------------------------------------------------------------- DP recursion, one gap level
// out[l,i,j,b] = LSE_{k in (i,j)} ( table[l,i,k] + table[i,k,j] + red_log[k,j] )
__global__ __launch_bounds__(256) void dp_kernel(
    const float* __restrict__ red_log, float* __restrict__ table, int gap)
{
    const int I = LL - gap;
    const int total = LL * I * BB;
    const int tid = blockIdx.x * 256 + threadIdx.x;
    if (tid >= total) return;
    const int b = tid & 7;
    const int t = tid >> 3;
    const int i = t % I;
    const int l = t / I;
    const int j = i + gap;

    const float* tli = table + (size_t)(l * LL + i) * LL * BB + b;      // +k*BB
    const float* tij = table + ((size_t)i * LL * LL + j) * BB + b;      // +k*LL*BB
    const float* rl  = red_log + (size_t)j * BB + b;                    // +k*LL*BB

    float m = -3.4e38f, s = 0.f;
    for (int k = i + 1; k < j; k++) {
        float x = tli[k * BB] + tij[k * (LL * BB)] + rl[k * (LL * BB)];
        if (x > m) { s = s * __expf(m - x) + 1.f; m = x; }
        else       { s += __expf(x - m); }
    }
    table[(((size_t)l * LL + i) * LL + j) * BB + b] = m + logf(s);
}

// ---------------------------------------------------------------- output
__global__ void out_kernel(const float* __restrict__ table, float* __restrict__ out) {
    const int b = threadIdx.x;
    if (b < BB) out[b] = table[((size_t)0 * LL * LL + NSENT) * BB + b];
}

// ---------------------------------------------------------------- launch
extern "C" void kernel_launch(void* const* d_in, const int* in_sizes, int n_in,
                              void* d_out, int out_size, void* d_ws, size_t ws_size,
                              hipStream_t stream) {
    const float* enc      = (const float*)d_in[0];
    const int*   sentence = (const int*)  d_in[1];
    const float* W1t      = (const float*)d_in[2];
    const float* b1t      = (const float*)d_in[3];
    const float* W2t      = (const float*)d_in[4];
    const float* b2t      = (const float*)d_in[5];
    const float* W1w      = (const float*)d_in[6];
    const float* b1w      = (const float*)d_in[7];
    const float* W2w      = (const float*)d_in[8];
    const float* b2w      = (const float*)d_in[9];
    float* out = (float*)d_out;

    char* ws = (char*)d_ws;
    float* table   = (float*)ws;                                   // 64*64*64*8*4 = 8 MB
    float* sh_log  = (float*)(ws + (size_t)LL * LL * LL * BB * 4); // 64*64*8*4 = 128 KB
    float* red_log = sh_log + LL * LL * BB;

    init_table_kernel<<<(LL * LL * LL * BB) / 256, 256, 0, stream>>>(table);
    trans_kernel<<<LL * LL, 256, 0, stream>>>(enc, W1t, b1t, W2t, b2t, sh_log, red_log);
    word_kernel<<<LL * LL, 256, 0, stream>>>(enc, sentence, W1w, b1w, W2w, b2w, sh_log, table);
    for (int gap = 2; gap <= NSENT; gap++) {
        const int I = LL - gap;
        const int total = LL * I * BB;
        dp_kernel<<<(total + 255) / 256, 256, 0, stream>>>(red_log, table, gap);
    }
    out_kernel<<<1, 64, 0, stream>>>(table, out);
}

// Round 3
// 779.641 us; speedup vs baseline: 5.6248x; 5.6248x over previous
//
#include <hip/hip_runtime.h>
#include <math.h>

#define LL 64
#define BB 8
#define HH 512
#define H2 1024
#define VV 8192
#define NSENT 63
#define NPAIR 2016          // i<j pairs
#define NPITEM 2017         // + root (0,0)
#define MROWS 16136         // 2017*8
#define MPAD 16256          // 127*128
#define NEGV (-1e9f)
#define EPSV 4.5399929762484854e-05f

typedef unsigned int uint;
typedef unsigned short ushort;
using bf16x8 = __attribute__((ext_vector_type(8))) short;
using f32x4  = __attribute__((ext_vector_type(4))) float;

__device__ inline ushort f2bf(float x) {   // round-to-nearest-even
    uint u = __float_as_uint(x);
    uint r = (u + 0x7fffu + ((u >> 16) & 1u)) >> 16;
    return (ushort)r;
}

// ---------------------------------------------------------------- init table
__global__ __launch_bounds__(256) void init_table_kernel(float* __restrict__ table) {
    table[blockIdx.x * 256 + threadIdx.x] = NEGV;
}

// ---------------------------------------------------------------- pair tables + words
__global__ __launch_bounds__(256) void pairtab_kernel(
    const int* __restrict__ sentence, int* __restrict__ pair_i,
    int* __restrict__ pair_j, int* __restrict__ words)
{
    const int p = blockIdx.x * 256 + threadIdx.x;
    if (p >= NPITEM) return;
    int i = 0, j = 0;
    if (p == NPAIR) { i = 0; j = 0; }
    else {
        int base = 0;
        while (i < 62 && p >= base + (NSENT - i)) { base += NSENT - i; i++; }
        j = i + 1 + (p - base);
    }
    pair_i[p] = i; pair_j[p] = j;
    for (int b = 0; b < BB; b++) {
        int w;
        if (p == NPAIR)      w = sentence[1 * BB + b];
        else if (j <= 62)    w = sentence[(j + 1) * BB + b];
        else                 w = -1;
        words[p * BB + b] = w;
    }
}

// ---------------------------------------------------------------- U/L factor GEMMs
// UL[mat][l*8+b][u] = enc[l][b][:] @ Wsel[:,u]; mat: 0=W1t_top 1=W1t_bot 2=W1w_top 3=W1w_bot
__global__ __launch_bounds__(256) void ul_kernel(
    const float* __restrict__ enc, const float* __restrict__ W1t,
    const float* __restrict__ W1w, float* __restrict__ UL)
{
    const int mat = blockIdx.x >> 6;
    const int l = blockIdx.x & 63;
    __shared__ float f[BB][HH];    // 16 KB
    for (int t = threadIdx.x; t < BB * HH; t += 256)
        f[t >> 9][t & 511] = enc[(size_t)l * BB * HH + t];
    __syncthreads();

    const float* W = (mat == 0) ? W1t : (mat == 1) ? (W1t + HH * HH)
                   : (mat == 2) ? W1w : (W1w + HH * HH);
    const int u0 = threadIdx.x;
    float acc0[BB], acc1[BB];
#pragma unroll
    for (int b = 0; b < BB; b++) { acc0[b] = 0.f; acc1[b] = 0.f; }
    for (int k = 0; k < HH; k += 4) {
        float4 fk[BB];
#pragma unroll
        for (int b = 0; b < BB; b++) fk[b] = *(const float4*)&f[b][k];
#pragma unroll
        for (int kk = 0; kk < 4; kk++) {
            float w0 = W[(size_t)(k + kk) * HH + u0];
            float w1 = W[(size_t)(k + kk) * HH + u0 + 256];
#pragma unroll
            for (int b = 0; b < BB; b++) {
                float fb = ((const float*)&fk[b])[kk];
                acc0[b] = fmaf(fb, w0, acc0[b]);
                acc1[b] = fmaf(fb, w1, acc1[b]);
            }
        }
    }
    float* out = UL + (size_t)mat * 512 * 512 + (size_t)(l * BB) * HH;
#pragma unroll
    for (int b = 0; b < BB; b++) {
        out[b * HH + u0]       = acc0[b];
        out[b * HH + u0 + 256] = acc1[b];
    }
}

// ---------------------------------------------------------------- W2w -> bf16 transposed [N][K]
__global__ __launch_bounds__(256) void w2wt_kernel(
    const float* __restrict__ W2w, ushort* __restrict__ W2wT)
{
    const int kt = blockIdx.x >> 7;      // 0..7   (K tiles of 64)
    const int nt = blockIdx.x & 127;     // 0..127 (N tiles of 64)
    const int k0 = kt * 64, n0 = nt * 64;
    __shared__ float tile[64][65];
    for (int it = 0; it < 16; it++) {
        int idx = it * 256 + threadIdx.x;
        int kr = idx >> 6, nc = idx & 63;
        tile[kr][nc] = W2w[(size_t)(k0 + kr) * VV + n0 + nc];
    }
    __syncthreads();
    for (int it = 0; it < 16; it++) {
        int idx = it * 256 + threadIdx.x;
        int nr = idx >> 6, kc = idx & 63;
        W2wT[(size_t)(n0 + nr) * HH + k0 + kc] = f2bf(tile[kc][nr]);
    }
}

// ---------------------------------------------------------------- per-pair: trans probs + hidden_w (bf16)
__global__ __launch_bounds__(256) void pairs_kernel(
    const float* __restrict__ UL, const float* __restrict__ b1t,
    const float* __restrict__ W2t, const float* __restrict__ b2t,
    const float* __restrict__ b1w, const int* __restrict__ pair_i,
    const int* __restrict__ pair_j, float* __restrict__ sh_log,
    float* __restrict__ red_log, ushort* __restrict__ hbf)
{
    const int p = blockIdx.x;
    const int i = pair_i[p], j = pair_j[p];
    const float* Ut = UL;
    const float* Lt = UL + 512 * 512;
    const float* Uw = UL + 2 * 512 * 512;
    const float* Lw = UL + 3 * 512 * 512;

    __shared__ float redm[4][BB];
    const int k0 = threadIdx.x * 2;
    const float2 b1wv = *(const float2*)&b1w[k0];
    const float2 b1tv = *(const float2*)&b1t[k0];
    const float2 w2tv = *(const float2*)&W2t[k0];

    float part[BB];
#pragma unroll
    for (int b = 0; b < BB; b++) {
        // word hidden
        float2 u = *(const float2*)&Uw[(size_t)(i * BB + b) * HH + k0];
        float2 l = *(const float2*)&Lw[(size_t)(j * BB + b) * HH + k0];
        float h0 = u.x + l.x + b1wv.x; h0 = h0 > 0.f ? h0 : 0.f;
        float h1 = u.y + l.y + b1wv.y; h1 = h1 > 0.f ? h1 : 0.f;
        uint packed = (uint)f2bf(h0) | ((uint)f2bf(h1) << 16);
        *(uint*)&hbf[(size_t)(p * BB + b) * HH + k0] = packed;
        // trans hidden -> partial score
        float2 ut = *(const float2*)&Ut[(size_t)(i * BB + b) * HH + k0];
        float2 lt = *(const float2*)&Lt[(size_t)(j * BB + b) * HH + k0];
        float t0 = ut.x + lt.x + b1tv.x; t0 = t0 > 0.f ? t0 : 0.f;
        float t1 = ut.y + lt.y + b1tv.y; t1 = t1 > 0.f ? t1 : 0.f;
        part[b] = t0 * w2tv.x + t1 * w2tv.y;
    }
    if (p == NPAIR) return;   // root: no trans

#pragma unroll
    for (int off = 32; off > 0; off >>= 1)
#pragma unroll
        for (int b = 0; b < BB; b++) part[b] += __shfl_down(part[b], off, 64);
    const int wave = threadIdx.x >> 6, lane = threadIdx.x & 63;
    if (lane == 0)
#pragma unroll
        for (int b = 0; b < BB; b++) redm[wave][b] = part[b];
    __syncthreads();
    if (threadIdx.x < BB) {
        const int b = threadIdx.x;
        float sc = redm[0][b] + redm[1][b] + redm[2][b] + redm[3][b] + b2t[0];
        float pr = 1.f / (1.f + expf(-sc));
        sh_log[(i * LL + j) * BB + b]  = log1pf(-pr + EPSV);
        red_log[(i * LL + j) * BB + b] = logf(pr + EPSV);
    }
}

// ---------------------------------------------------------------- logits GEMM (MFMA) + per-tile LSE partials
// C = h[MPAD,512]bf16 @ W2wT[8192,512]bf16^T + b2w
// partials indexed (nt*2 + wn): each wave-column-half gets its own slot (fixes R2 race)
__global__ __launch_bounds__(256) void gemm_kernel(
    const ushort* __restrict__ hA, const ushort* __restrict__ w2wT,
    const float* __restrict__ b2w, const int* __restrict__ words,
    float* __restrict__ part_m, float* __restrict__ part_s,
    float* __restrict__ gval)
{
    const int mt = blockIdx.x >> 6;
    const int nt = blockIdx.x & 63;
    const int mrow0 = mt * 128, ncol0 = nt * 128;

    __shared__ ushort As[128 * 72];   // 18 KB, row-major [m][k], pad 72
    __shared__ ushort Bs[128 * 72];   // 18 KB, [n][k]

    const int tid = threadIdx.x;
    const int lane = tid & 63, wid = tid >> 6;
    const int wm = wid >> 1, wn = wid & 1;
    const int quad = lane >> 4, l15 = lane & 15;

    f32x4 acc[4][4];
#pragma unroll
    for (int a = 0; a < 4; a++)
#pragma unroll
        for (int b = 0; b < 4; b++) acc[a][b] = (f32x4){0.f, 0.f, 0.f, 0.f};

    for (int kc = 0; kc < 8; kc++) {
        const int k0 = kc * 64;
        __syncthreads();
#pragma unroll
        for (int it = 0; it < 4; it++) {
            int slot = it * 256 + tid;
            int row = slot >> 3, ks = (slot & 7) * 8;
            *(uint4*)&As[row * 72 + ks] =
                *(const uint4*)&hA[(size_t)(mrow0 + row) * HH + k0 + ks];
            *(uint4*)&Bs[row * 72 + ks] =
                *(const uint4*)&w2wT[(size_t)(ncol0 + row) * HH + k0 + ks];
        }
        __syncthreads();
#pragma unroll
        for (int ks = 0; ks < 2; ks++) {
            const int ko = ks * 32 + quad * 8;
            bf16x8 af[4], bfr[4];
#pragma unroll
            for (int fm = 0; fm < 4; fm++)
                af[fm] = *(const bf16x8*)&As[(wm * 64 + fm * 16 + l15) * 72 + ko];
#pragma unroll
            for (int fn = 0; fn < 4; fn++)
                bfr[fn] = *(const bf16x8*)&Bs[(wn * 64 + fn * 16 + l15) * 72 + ko];
#pragma unroll
            for (int fm = 0; fm < 4; fm++)
#pragma unroll
                for (int fn = 0; fn < 4; fn++)
                    acc[fm][fn] = __builtin_amdgcn_mfma_f32_16x16x32_bf16(
                        af[fm], bfr[fn], acc[fm][fn], 0, 0, 0);
        }
    }

    // epilogue: bias + per-row (m,s) over this wave's 64 cols
    float bias[4];
    int gcol[4];
#pragma unroll
    for (int fn = 0; fn < 4; fn++) {
        gcol[fn] = ncol0 + wn * 64 + fn * 16 + l15;
        bias[fn] = b2w[gcol[fn]];
    }
    const int pslot = nt * 2 + wn;
#pragma unroll
    for (int fm = 0; fm < 4; fm++) {
#pragma unroll
        for (int r = 0; r < 4; r++) {
            const int grow = mrow0 + wm * 64 + fm * 16 + quad * 4 + r;
            const int word = words[grow];
            float v[4];
#pragma unroll
            for (int fn = 0; fn < 4; fn++) {
                v[fn] = acc[fm][fn][r] + bias[fn];
                if (gcol[fn] == word) gval[grow] = v[fn];
            }
            float mx = fmaxf(fmaxf(v[0], v[1]), fmaxf(v[2], v[3]));
            float ss = __expf(v[0] - mx) + __expf(v[1] - mx)
                     + __expf(v[2] - mx) + __expf(v[3] - mx);
#pragma unroll
            for (int off = 1; off <= 8; off <<= 1) {
                float mo = __shfl_xor(mx, off, 64);
                float so = __shfl_xor(ss, off, 64);
                float M = fmaxf(mx, mo);
                ss = ss * __expf(mx - M) + so * __expf(mo - M);
                mx = M;
            }
            if (l15 == 0) {
                part_m[(size_t)pslot * MPAD + grow] = mx;
                part_s[(size_t)pslot * MPAD + grow] = ss;
            }
        }
    }
}

// ---------------------------------------------------------------- combine LSE partials -> base cells
__global__ __launch_bounds__(256) void combine_kernel(
    const float* __restrict__ part_m, const float* __restrict__ part_s,
    const float* __restrict__ gval, const float* __restrict__ sh_log,
    const int* __restrict__ pair_i, const int* __restrict__ pair_j,
    float* __restrict__ table)
{
    const int row = blockIdx.x * 256 + threadIdx.x;
    if (row >= MROWS) return;
    const int p = row >> 3, b = row & 7;
    float M = -3.4e38f, S = 0.f;
    for (int nt = 0; nt < 128; nt++) {
        float pm = part_m[(size_t)nt * MPAD + row];
        float ps = part_s[(size_t)nt * MPAD + row];
        float Mn = fmaxf(M, pm);
        S = S * __expf(M - Mn) + ps * __expf(pm - Mn);
        M = Mn;
    }
    const float lse = M + logf(S);
    const float g = gval[row] - lse;
    const int i = pair_i[p], j = pair_j[p];
    if (p == NPAIR) {
        table[(size_t)((0 * LL + 0) * LL + 1) * BB + b] = g;
    } else if (j <= 62) {
        table[(size_t)((i * LL + j) * LL + (j + 1)) * BB + b] =
            sh_log[(i * LL + j) * BB + b] + g;
    }
}

// ---------------------------------------------------------------- DP level (split-k x4)
__global__ __launch_bounds__(256) void dp_kernel(
    const float* __restrict__ red_log, float* __restrict__ table, int gap)
{
    const int I = LL - gap;
    const int total = LL * I * BB;
    const int tid4 = blockIdx.x * 256 + threadIdx.x;
    const int item = tid4 >> 2, sub = tid4 & 3;
    if (item >= total) return;
    const int b = item & 7;
    const int t = item >> 3;
    const int i = t % I;
    const int l = t / I;
    const int j = i + gap;

    const float* tli = table + (size_t)(l * LL + i) * LL * BB + b;
    const float* tij = table + ((size_t)i * LL * LL + j) * BB + b;
    const float* rl  = red_log + (size_t)j * BB + b;

    float m = -3.4e38f, s = 0.f;
    for (int k = i + 1 + sub; k < j; k += 4) {
        float x = tli[k * BB] + tij[k * (LL * BB)] + rl[k * (LL * BB)];
        if (x > m) { s = s * __expf(m - x) + 1.f; m = x; }
        else       { s += __expf(x - m); }
    }
#pragma unroll
    for (int off = 1; off <= 2; off <<= 1) {
        float mo = __shfl_xor(m, off, 64);
        float so = __shfl_xor(s, off, 64);
        float M = fmaxf(m, mo);
        s = s * __expf(m - M) + so * __expf(mo - M);
        m = M;
    }
    if (sub == 0)
        table[(((size_t)l * LL + i) * LL + j) * BB + b] = m + logf(s);
}

// ---------------------------------------------------------------- output
__global__ void out_kernel(const float* __restrict__ table, float* __restrict__ out) {
    const int b = threadIdx.x;
    if (b < BB) out[b] = table[((size_t)0 * LL * LL + NSENT) * BB + b];
}

// ---------------------------------------------------------------- launch
extern "C" void kernel_launch(void* const* d_in, const int* in_sizes, int n_in,
                              void* d_out, int out_size, void* d_ws, size_t ws_size,
                              hipStream_t stream) {
    const float* enc      = (const float*)d_in[0];
    const int*   sentence = (const int*)  d_in[1];
    const float* W1t      = (const float*)d_in[2];
    const float* b1t      = (const float*)d_in[3];
    const float* W2t      = (const float*)d_in[4];
    const float* b2t      = (const float*)d_in[5];
    const float* W1w      = (const float*)d_in[6];
    const float* b1w      = (const float*)d_in[7];
    const float* W2w      = (const float*)d_in[8];
    const float* b2w      = (const float*)d_in[9];
    float* out = (float*)d_out;

    float* base = (float*)d_ws;
    float* table   = base;                 base += (size_t)LL * LL * LL * BB;   // 2,097,152
    float* sh_log  = base;                 base += LL * LL * BB;                // 32768
    float* red_log = base;                 base += LL * LL * BB;                // 32768
    float* UL      = base;                 base += 4 * 512 * 512;               // 1,048,576
    float* part_m  = base;                 base += (size_t)128 * MPAD;
    float* part_s  = base;                 base += (size_t)128 * MPAD;
    float* gval    = base;                 base += MPAD;
    int*   words   = (int*)base;           base += MPAD;
    int*   pair_i  = (int*)base;           base += 2048;
    int*   pair_j  = (int*)base;           base += 2048;
    ushort* hbf    = (ushort*)base;        base += (size_t)MPAD * HH / 2;
    ushort* w2wT   = (ushort*)base;        base += (size_t)VV * HH / 2;

    init_table_kernel<<<(LL * LL * LL * BB) / 256, 256, 0, stream>>>(table);
    pairtab_kernel<<<8, 256, 0, stream>>>(sentence, pair_i, pair_j, words);
    ul_kernel<<<256, 256, 0, stream>>>(enc, W1t, W1w, UL);
    w2wt_kernel<<<1024, 256, 0, stream>>>(W2w, w2wT);
    pairs_kernel<<<NPITEM, 256, 0, stream>>>(UL, b1t, W2t, b2t, b1w,
                                             pair_i, pair_j, sh_log, red_log, hbf);
    gemm_kernel<<<127 * 64, 256, 0, stream>>>(hbf, w2wT, b2w, words,
                                              part_m, part_s, gval);
    combine_kernel<<<64, 256, 0, stream>>>(part_m, part_s, gval, sh_log,
                                           pair_i, pair_j, table);
    for (int gap = 2; gap <= NSENT; gap++) {
        const int I = LL - gap;
        const int total = LL * I * BB * 4;
        dp_kernel<<<(total + 255) / 256, 256, 0, stream>>>(red_log, table, gap);
    }
    out_kernel<<<1, 64, 0, stream>>>(table, out);
}